// Round 6
// baseline (1033.698 us; speedup 1.0000x reference)
//
#include <hip/hip_runtime.h>

// GCN: 2x GraphConv(norm='both') + leaky_relu + linear classifier.
// Literal transliteration, all-f32 internal, atomic aggregation.
// OUTPUT: f32 (the reference's true output dtype; prior rounds wrote bf16 and
// were scrambled on readback). Input dtypes device-detected per buffer.

__device__ __forceinline__ float b2f(unsigned short u) {
    return __uint_as_float(((unsigned int)u) << 16);
}
__device__ __forceinline__ unsigned short f2b(float f) {
    unsigned int i = __float_as_uint(f);
    unsigned int r = (i + 0x7FFFu + ((i >> 16) & 1u)) >> 16;  // RNE
    return (unsigned short)r;
}

// flag=1 if float buffer is f32 (u16 low-halves look like huge exponents)
__global__ void detect_f32_kernel(const unsigned short* __restrict__ p, int nwords, int* flag) {
    __shared__ int cnt;
    if (threadIdx.x == 0) cnt = 0;
    __syncthreads();
    int c = 0;
    for (int i = threadIdx.x; i < nwords; i += 256) {
        unsigned e = (p[i] >> 7) & 0xFFu;
        if (e >= 0xC0u) c++;
    }
    atomicAdd(&cnt, c);
    __syncthreads();
    if (threadIdx.x == 0) flag[0] = (cnt > nwords / 64) ? 1 : 0;
}

// flag=1 if index buffer is int64 (odd u32 words ~all zero)
__global__ void detect_i64_kernel(const unsigned int* __restrict__ p, int npairs, int* flag) {
    __shared__ int cnt;
    if (threadIdx.x == 0) cnt = 0;
    __syncthreads();
    int c = 0;
    for (int i = threadIdx.x; i < npairs; i += 256) {
        if (p[2 * i + 1] != 0u) c++;
    }
    atomicAdd(&cnt, c);
    __syncthreads();
    if (threadIdx.x == 0) flag[0] = (cnt < npairs / 10) ? 1 : 0;
}

__device__ __forceinline__ float load_flt(const void* p, int i, int isf32) {
    return isf32 ? ((const float*)p)[i] : b2f(((const unsigned short*)p)[i]);
}
__device__ __forceinline__ int ld_idx(const void* p, int i, int is64) {
    return is64 ? (int)((const long long*)p)[i] : ((const int*)p)[i];
}

__global__ void conv_buf_kernel(const void* __restrict__ p, const int* __restrict__ flag,
                                float* __restrict__ q, int cnt) {
    int i = blockIdx.x * blockDim.x + threadIdx.x;
    if (i < cnt) q[i] = load_flt(p, i, flag[0]);
}

__global__ void deg_kernel(const void* __restrict__ src, const void* __restrict__ dst,
                           const int* __restrict__ iflag, int* dout, int* din, int e) {
    int i = blockIdx.x * blockDim.x + threadIdx.x;
    int is64 = iflag[0];
    if (i < e) {
        atomicAdd(&dout[ld_idx(src, i, is64)], 1);
        atomicAdd(&din[ld_idx(dst, i, is64)], 1);
    }
}

__global__ void isq_kernel(const int* __restrict__ dout, const int* __restrict__ din,
                           float* oi, float* ii, int n) {
    int i = blockIdx.x * blockDim.x + threadIdx.x;
    if (i < n) {
        oi[i] = rsqrtf((float)max(dout[i], 1));
        ii[i] = rsqrtf((float)max(din[i], 1));
    }
}

// A[i] = x[i] * oi[i/D]   (dtype-flexible source)
__global__ void scale_x_kernel(const void* __restrict__ x, const int* __restrict__ xflag,
                               const float* __restrict__ oi, float* A, int D, int total) {
    int i = blockIdx.x * blockDim.x + threadIdx.x;
    if (i < total) A[i] = load_flt(x, i, xflag[0]) * oi[i / D];
}

// A[i] = H[i] * oi[i/D]
__global__ void scale_f_kernel(const float* __restrict__ H, const float* __restrict__ oi,
                               float* A, int D, int total) {
    int i = blockIdx.x * blockDim.x + threadIdx.x;
    if (i < total) A[i] = H[i] * oi[i / D];
}

// B[dst*D+f] += A[src*D+f], thread per (edge, f)
__global__ void agg_kernel(const float* __restrict__ A, const void* __restrict__ src,
                           const void* __restrict__ dst, const int* __restrict__ iflag,
                           float* B, int D, int total) {
    int i = blockIdx.x * blockDim.x + threadIdx.x;
    if (i < total) {
        int edge = i / D, f = i - edge * D;
        int is64 = iflag[0];
        int s = ld_idx(src, edge, is64);
        int d = ld_idx(dst, edge, is64);
        atomicAdd(&B[d * D + f], A[s * D + f]);
    }
}

// H[v*Dout+j] = leaky( (sum_k B[v*Din+k] * W[k*Dout+j]) * ii[v] + b[j] )
__global__ void transform_kernel(const float* __restrict__ B, const float* __restrict__ ii,
                                 const float* __restrict__ W, const float* __restrict__ bias,
                                 float* __restrict__ H, int Din, int Dout, int total) {
    int i = blockIdx.x * blockDim.x + threadIdx.x;
    if (i >= total) return;
    int v = i / Dout, j = i - v * Dout;
    const float* r = B + (size_t)v * Din;
    float o = 0.f;
    for (int k = 0; k < Din; k++) o = fmaf(r[k], W[k * Dout + j], o);
    o = fmaf(o, ii[v], bias[j]);
    H[i] = (o > 0.f) ? o : 0.01f * o;
}

// out[v*C+c] = f32( sum_k H[v*Din+k] * Wc[k*C+c] + bc[c] )   (no activation)
__global__ void classifier_kernel(const float* __restrict__ H, const float* __restrict__ Wc,
                                  const float* __restrict__ bc, float* __restrict__ out,
                                  int Din, int C, int total) {
    int i = blockIdx.x * blockDim.x + threadIdx.x;
    if (i >= total) return;
    int v = i / C, c = i - v * C;
    const float* r = H + (size_t)v * Din;
    float o = bc[c];
    for (int k = 0; k < Din; k++) o = fmaf(r[k], Wc[k * C + c], o);
    out[i] = o;
}

__global__ void sentinel_kernel(float* out, float val) {
    if (threadIdx.x == 0 && blockIdx.x == 0) out[0] = val;
}

extern "C" void kernel_launch(void* const* d_in, const int* in_sizes, int n_in,
                              void* d_out, int out_size, void* d_ws, size_t ws_size,
                              hipStream_t stream) {
    const void* x  = d_in[0];
    const void* src = d_in[1];
    const void* dst = d_in[2];

    // ---- derive all dims from sizes; on inconsistency exfiltrate code ----
    int bad = 0;
    int C = 0, D = 0, H1 = 0, H2 = 0, E = 0;
    long long N = 0;
    if (n_in != 9) bad = 1;
    if (!bad) {
        C = in_sizes[8];
        if (C <= 0 || out_size % C != 0) bad = 2;
    }
    if (!bad) {
        N = out_size / C;
        if (N <= 0 || in_sizes[0] % N != 0) bad = 3;
    }
    if (!bad) {
        D = (int)(in_sizes[0] / N);
        H1 = in_sizes[4];
        H2 = in_sizes[6];
        E = in_sizes[1];
        if ((long long)in_sizes[3] != (long long)D * H1) bad = 4;
        else if ((long long)in_sizes[5] != (long long)H1 * H2) bad = 5;
        else if ((long long)in_sizes[7] != (long long)H2 * C) bad = 6;
        else if (in_sizes[2] != E) bad = 7;
    }
    int Dmax = 0, Hmax = 0, wtot = 0;
    size_t need = 0;
    if (!bad) {
        Dmax = (D > H1) ? D : H1;
        Hmax = (H1 > H2) ? H1 : H2;
        wtot = D * H1 + H1 + H1 * H2 + H2 + H2 * C + C;
        need = (size_t)N * 16 + 1024 * 3 + (size_t)wtot * 4 +
               (size_t)N * 4 * (2 * (size_t)Dmax + Hmax) + 4096;
        if (ws_size < need) bad = 8;
    }
    if (bad) {
        sentinel_kernel<<<1, 64, 0, stream>>>((float*)d_out, ldexpf(1.f, 20 + bad));
        return;
    }

    char* ws = (char*)d_ws;
    size_t off = 0;
    auto take = [&](size_t bytes) -> char* {
        char* p = ws + off;
        off = (off + bytes + 255) & ~(size_t)255;
        return p;
    };
    int* deg_out = (int*)take((size_t)N * 4);
    int* deg_in  = (int*)take((size_t)N * 4);
    int* xflag   = (int*)take(256);
    int* wflag   = (int*)take(256);
    int* iflag   = (int*)take(256);
    float* oi    = (float*)take((size_t)N * 4);
    float* ii    = (float*)take((size_t)N * 4);
    float* wbuf  = (float*)take((size_t)wtot * 4);
    float* A     = (float*)take((size_t)N * Dmax * 4);
    float* B     = (float*)take((size_t)N * Dmax * 4);
    float* Hbuf  = (float*)take((size_t)N * Hmax * 4);

    float* w1c = wbuf;
    float* b1c = w1c + D * H1;
    float* w2c = b1c + H1;
    float* b2c = w2c + H1 * H2;
    float* wcc = b2c + H2;
    float* bcc = wcc + H2 * C;

    const int tb = 256;
    auto blocks = [&](long long t) { return (int)((t + tb - 1) / tb); };
    int n = (int)N;

    hipMemsetAsync(deg_out, 0, (size_t)N * 4, stream);
    hipMemsetAsync(deg_in, 0, (size_t)N * 4, stream);

    detect_f32_kernel<<<1, tb, 0, stream>>>((const unsigned short*)x,
                                            (int)((N * D < 8192) ? N * D : 8192), xflag);
    detect_f32_kernel<<<1, tb, 0, stream>>>((const unsigned short*)d_in[3],
                                            (D * H1 < 8192) ? D * H1 : 8192, wflag);
    {
        int npairs = (E / 2 < 1024) ? E / 2 : 1024;
        detect_i64_kernel<<<1, tb, 0, stream>>>((const unsigned int*)src, npairs, iflag);
    }
    conv_buf_kernel<<<blocks(D * H1), tb, 0, stream>>>(d_in[3], wflag, w1c, D * H1);
    conv_buf_kernel<<<blocks(H1), tb, 0, stream>>>(d_in[4], wflag, b1c, H1);
    conv_buf_kernel<<<blocks(H1 * H2), tb, 0, stream>>>(d_in[5], wflag, w2c, H1 * H2);
    conv_buf_kernel<<<blocks(H2), tb, 0, stream>>>(d_in[6], wflag, b2c, H2);
    conv_buf_kernel<<<blocks(H2 * C), tb, 0, stream>>>(d_in[7], wflag, wcc, H2 * C);
    conv_buf_kernel<<<blocks(C), tb, 0, stream>>>(d_in[8], wflag, bcc, C);

    deg_kernel<<<blocks(E), tb, 0, stream>>>(src, dst, iflag, deg_out, deg_in, E);
    isq_kernel<<<blocks(N), tb, 0, stream>>>(deg_out, deg_in, oi, ii, n);

    // ---- layer 1 ----
    scale_x_kernel<<<blocks(N * D), tb, 0, stream>>>(x, xflag, oi, A, D, (int)(N * D));
    hipMemsetAsync(B, 0, (size_t)N * D * 4, stream);
    agg_kernel<<<blocks((long long)E * D), tb, 0, stream>>>(A, src, dst, iflag, B, D,
                                                            (int)((long long)E * D));
    transform_kernel<<<blocks(N * H1), tb, 0, stream>>>(B, ii, w1c, b1c, Hbuf, D, H1,
                                                        (int)(N * H1));
    // ---- layer 2 ----
    scale_f_kernel<<<blocks(N * H1), tb, 0, stream>>>(Hbuf, oi, A, H1, (int)(N * H1));
    hipMemsetAsync(B, 0, (size_t)N * H1 * 4, stream);
    agg_kernel<<<blocks((long long)E * H1), tb, 0, stream>>>(A, src, dst, iflag, B, H1,
                                                             (int)((long long)E * H1));
    transform_kernel<<<blocks(N * H2), tb, 0, stream>>>(B, ii, w2c, b2c, Hbuf, H1, H2,
                                                        (int)(N * H2));
    // ---- classifier (f32 out) ----
    classifier_kernel<<<blocks(N * C), tb, 0, stream>>>(Hbuf, wcc, bcc,
                                                        (float*)d_out, H2, C,
                                                        (int)(N * C));
}

// Round 7
// 438.396 us; speedup vs baseline: 2.3579x; 2.3579x over previous
//
#include <hip/hip_runtime.h>

// GCN: 2x GraphConv(norm='both') + leaky_relu + linear classifier.
// Interface (validated R6): x/W/b f32, src/dst int32, out f32.
// Design: CSR-by-dst built once; per layer one fused gather+matvec kernel
// (wave per node, lane = feature, W column in VGPRs, readlane broadcast).
// Out-degree scaling pre-folded into staged features; classifier fused.

__global__ void deg_kernel(const int* __restrict__ src, const int* __restrict__ dst,
                           int* dout, int* din, int e) {
    int i = blockIdx.x * blockDim.x + threadIdx.x;
    if (i < e) {
        atomicAdd(&dout[src[i]], 1);
        atomicAdd(&din[dst[i]], 1);
    }
}

__global__ void isq_kernel(const int* __restrict__ dout, const int* __restrict__ din,
                           float* oi, float* ii, int n) {
    int i = blockIdx.x * blockDim.x + threadIdx.x;
    if (i < n) {
        oi[i] = rsqrtf((float)max(dout[i], 1));
        ii[i] = rsqrtf((float)max(din[i], 1));
    }
}

// ---- exclusive prefix scan of deg_in -> row offsets (3 kernels) ----
__global__ void scan1_kernel(const int* __restrict__ deg, int* row, int* partials, int n) {
    __shared__ int s[1024];
    int t = threadIdx.x;
    int i = blockIdx.x * 1024 + t;
    int v = (i < n) ? deg[i] : 0;
    s[t] = v;
    __syncthreads();
    for (int d = 1; d < 1024; d <<= 1) {
        int x = (t >= d) ? s[t - d] : 0;
        __syncthreads();
        s[t] += x;
        __syncthreads();
    }
    if (i < n) row[i] = s[t] - v;  // exclusive within chunk
    if (t == 1023) partials[blockIdx.x] = s[1023];
}

__global__ void scan2_kernel(int* partials, int nchunks, int* row, int n) {
    if (threadIdx.x == 0 && blockIdx.x == 0) {
        int acc = 0;
        for (int c = 0; c < nchunks; c++) { int v = partials[c]; partials[c] = acc; acc += v; }
        row[n] = acc;  // == E
    }
}

__global__ void scan3_kernel(int* row, const int* __restrict__ partials, int n) {
    int i = blockIdx.x * blockDim.x + threadIdx.x;
    if (i < n) row[i] += partials[i >> 10];
}

__global__ void scatter_kernel(const int* __restrict__ src, const int* __restrict__ dst,
                               const int* __restrict__ row, int* cursor, int* csr, int e) {
    int i = blockIdx.x * blockDim.x + threadIdx.x;
    if (i < e) {
        int d = dst[i];
        int p = row[d] + atomicAdd(&cursor[d], 1);
        csr[p] = src[i];
    }
}

// xs[i] = x[i] * oi[i>>6]  (pre-fold source out-degree scaling)
__global__ void xscale_kernel(const float* __restrict__ x, const float* __restrict__ oi,
                              float* xs, int total) {
    int i = blockIdx.x * blockDim.x + threadIdx.x;
    if (i < total) xs[i] = x[i] * oi[i >> 6];
}

// One wave per node (grid-stride). Lane = feature. W column in 64 VGPRs;
// aggregated row broadcast via readlane. Layer-1 output pre-scaled by oi.
// FINAL: classifier fused (64->2), writes float2 per node.
template <bool FINAL>
__global__ __launch_bounds__(256) void layer_kernel(
    const float* __restrict__ feat, const int* __restrict__ row,
    const int* __restrict__ csr, const float* __restrict__ ii,
    const float* __restrict__ oi,
    const float* __restrict__ W, const float* __restrict__ bias,
    const float* __restrict__ Wc, const float* __restrict__ bcl,
    float* __restrict__ out, int n, int nwaves) {
    int lane = threadIdx.x & 63;
    int wid = blockIdx.x * (blockDim.x >> 6) + (threadIdx.x >> 6);

    float wreg[64];
#pragma unroll
    for (int k = 0; k < 64; k++) wreg[k] = W[k * 64 + lane];  // column `lane`
    float bl = bias[lane];
    float wc0 = 0.f, wc1 = 0.f, bc0 = 0.f, bc1 = 0.f;
    if constexpr (FINAL) {
        wc0 = Wc[lane * 2];
        wc1 = Wc[lane * 2 + 1];
        bc0 = bcl[0];
        bc1 = bcl[1];
    }

    for (int v = wid; v < n; v += nwaves) {
        int s0 = row[v], s1 = row[v + 1];
        float acc = 0.f;
        int i = s0;
        for (; i + 3 < s1; i += 4) {  // unroll 4: more loads in flight
            int u0 = csr[i], u1 = csr[i + 1], u2 = csr[i + 2], u3 = csr[i + 3];
            float a0 = feat[u0 * 64 + lane];
            float a1 = feat[u1 * 64 + lane];
            float a2 = feat[u2 * 64 + lane];
            float a3 = feat[u3 * 64 + lane];
            acc += a0 + a1 + a2 + a3;
        }
        for (; i < s1; i++) acc += feat[csr[i] * 64 + lane];

        float t = acc * ii[v];  // lane k holds aggregated row element k
        float o = bl;
#pragma unroll
        for (int k = 0; k < 64; k++) {
            float bk = __uint_as_float(
                (unsigned)__builtin_amdgcn_readlane((int)__float_as_uint(t), k));
            o = fmaf(bk, wreg[k], o);
        }
        o = (o > 0.f) ? o : 0.01f * o;  // leaky relu

        if constexpr (!FINAL) {
            out[v * 64 + lane] = o * oi[v];  // pre-scale for next layer's gather
        } else {
            float p0 = o * wc0, p1 = o * wc1;
#pragma unroll
            for (int off = 32; off; off >>= 1) {
                p0 += __shfl_down(p0, off);
                p1 += __shfl_down(p1, off);
            }
            if (lane == 0) {
                ((float2*)out)[v] = make_float2(p0 + bc0, p1 + bc1);
            }
        }
    }
}

extern "C" void kernel_launch(void* const* d_in, const int* in_sizes, int n_in,
                              void* d_out, int out_size, void* d_ws, size_t ws_size,
                              hipStream_t stream) {
    const float* x  = (const float*)d_in[0];
    const int* src  = (const int*)d_in[1];
    const int* dst  = (const int*)d_in[2];
    const float* W1 = (const float*)d_in[3];
    const float* b1 = (const float*)d_in[4];
    const float* W2 = (const float*)d_in[5];
    const float* b2 = (const float*)d_in[6];
    const float* Wc = (const float*)d_in[7];
    const float* bc = (const float*)d_in[8];
    int n = in_sizes[0] / 64;
    int e = in_sizes[1];
    int total = n * 64;

    char* ws = (char*)d_ws;
    size_t off = 0;
    auto take = [&](size_t bytes) -> char* {
        char* p = ws + off;
        off = (off + bytes + 255) & ~(size_t)255;
        return p;
    };
    int* deg_out  = (int*)take((size_t)n * 4);
    int* deg_in   = (int*)take((size_t)n * 4);
    int* cursor   = (int*)take((size_t)n * 4);
    int* row      = (int*)take((size_t)(n + 1) * 4);
    int* partials = (int*)take(4096);
    int* csr      = (int*)take((size_t)e * 4);
    float* oi     = (float*)take((size_t)n * 4);
    float* ii     = (float*)take((size_t)n * 4);
    float* xs     = (float*)take((size_t)total * 4);   // 25.6 MB
    float* h1s    = (float*)take((size_t)total * 4);   // 25.6 MB

    const int tb = 256;
    // zero deg_out, deg_in, cursor in one shot (contiguous carve-out)
    size_t zbytes = (size_t)((char*)cursor + (size_t)n * 4 - (char*)deg_out);
    hipMemsetAsync(deg_out, 0, zbytes, stream);

    deg_kernel<<<(e + tb - 1) / tb, tb, 0, stream>>>(src, dst, deg_out, deg_in, e);
    isq_kernel<<<(n + tb - 1) / tb, tb, 0, stream>>>(deg_out, deg_in, oi, ii, n);

    int nchunks = (n + 1023) / 1024;
    scan1_kernel<<<nchunks, 1024, 0, stream>>>(deg_in, row, partials, n);
    scan2_kernel<<<1, 64, 0, stream>>>(partials, nchunks, row, n);
    scan3_kernel<<<(n + tb - 1) / tb, tb, 0, stream>>>(row, partials, n);
    scatter_kernel<<<(e + tb - 1) / tb, tb, 0, stream>>>(src, dst, row, cursor, csr, e);
    xscale_kernel<<<(total + tb - 1) / tb, tb, 0, stream>>>(x, oi, xs, total);

    const int lblocks = 1024;                  // 4096 waves, ~24 nodes/wave
    const int nwaves = lblocks * (tb / 64);
    layer_kernel<false><<<lblocks, tb, 0, stream>>>(xs, row, csr, ii, oi, W1, b1,
                                                    nullptr, nullptr, h1s, n, nwaves);
    layer_kernel<true><<<lblocks, tb, 0, stream>>>(h1s, row, csr, ii, oi, W2, b2,
                                                   Wc, bc, (float*)d_out, n, nwaves);
}